// Round 4
// baseline (157.567 us; speedup 1.0000x reference)
//
#include <hip/hip_runtime.h>

// Shapes (fixed by the reference): B=16, F=4096, M=512, D=256, VE=64, H=512, V=50, OUT=8
#define B_DIM  16
#define F_DIM  4096
#define M_DIM  512
#define D_DIM  256
#define VE_DIM 64
#define H_DIM  512
#define K_DIM  320   // D + VE
#define OUT_DIM 8

#define NMORA        (B_DIM * M_DIM)          // 8192
#define SUMS_FLOATS  (NMORA * D_DIM)          // 2,097,152 (8.39 MB)
#define FOLD_BLOCKS  642
#define ZBLOCKS      514                      // 514*256*4 float4 = (SUMS_FLOATS+NMORA)/4 exactly

// ---------------------------------------------------------------------------
// K1 prep: blocks [0,642): fold WcT[o][k] = sum_j W_mora[k,j]*W_post[j,o]
//          and bc[o] = b_mora.W_post[:,o] + b_post[o]   (wave per (k,o))
//          blocks [642,1156): zero sums[8192][256] + cnt[8192] (exact cover)
// ---------------------------------------------------------------------------
__global__ __launch_bounds__(256) void prep_kernel(
    const float* __restrict__ W_mora,            // [320,512]
    const float* __restrict__ b_mora,            // [512]
    const float* __restrict__ W_post,            // [512,8]
    const float* __restrict__ b_post,            // [8]
    float* __restrict__ WcT,                     // [8,320] out
    float* __restrict__ bc,                      // [8] out
    float* __restrict__ zero_base)               // sums+cnt region
{
    const int blk = blockIdx.x;
    const int tid = threadIdx.x;
    if (blk < FOLD_BLOCKS) {
        const int w    = blk * 4 + (tid >> 6);   // global wave id
        const int lane = tid & 63;
        float sum = 0.f;
        if (w < 2560) {
            const int k = w >> 3, o = w & 7;
            const float* arow = W_mora + k * H_DIM;
            #pragma unroll
            for (int it = 0; it < H_DIM / 64; ++it) {
                const int j = lane + it * 64;
                sum += arow[j] * W_post[j * OUT_DIM + o];
            }
            #pragma unroll
            for (int off = 32; off >= 1; off >>= 1) sum += __shfl_down(sum, off, 64);
            if (lane == 0) WcT[o * K_DIM + k] = sum;
        } else if (w < 2568) {                    // bias fold
            const int o = w - 2560;
            #pragma unroll
            for (int it = 0; it < H_DIM / 64; ++it) {
                const int j = lane + it * 64;
                sum += b_mora[j] * W_post[j * OUT_DIM + o];
            }
            #pragma unroll
            for (int off = 32; off >= 1; off >>= 1) sum += __shfl_down(sum, off, 64);
            if (lane == 0) bc[o] = sum + b_post[o];
        }
    } else {
        const int zb = blk - FOLD_BLOCKS;         // 0..513
        float4* z = (float4*)zero_base;
        #pragma unroll
        for (int j = 0; j < 4; ++j)
            z[zb * 1024 + j * 256 + tid] = make_float4(0.f, 0.f, 0.f, 0.f);
    }
}

// ---------------------------------------------------------------------------
// K2 seg_sum: grid 1024x256 = 4 blocks/CU, single generation, no LDS/barriers.
// Each wave: 16 contiguous frames of one batch. Preload 16 mora indices,
// stream float4 loads 8-deep, segmented-accumulate in registers (wave-uniform
// run boundaries since all lanes share the frame's index), flush each run
// with per-lane global fp32 atomics; lane 0 accumulates the frame count.
// ---------------------------------------------------------------------------
__device__ __forceinline__ void flush_run(float* __restrict__ sums,
                                          float* __restrict__ cnt,
                                          int gm, const float4& a, int n, int lane)
{
    float* base = sums + (size_t)gm * D_DIM + lane * 4;
    atomicAdd(base + 0, a.x);
    atomicAdd(base + 1, a.y);
    atomicAdd(base + 2, a.z);
    atomicAdd(base + 3, a.w);
    if (lane == 0) atomicAdd(cnt + gm, (float)n);
}

__global__ __launch_bounds__(256) void seg_sum_kernel(
    const float* __restrict__ features,          // [B,F,D]
    const int* __restrict__ mora_index,          // [B,F]
    float* __restrict__ sums,                    // [8192,256]
    float* __restrict__ cnt)                     // [8192]
{
    const int gw   = blockIdx.x * 4 + (threadIdx.x >> 6);  // 0..4095
    const int lane = threadIdx.x & 63;
    const int b    = gw >> 8;                    // 256 waves per batch
    const int f0   = (gw & 255) * 16;

    const int* mi = mora_index + b * F_DIM + f0;
    int idx[16];
    #pragma unroll
    for (int i = 0; i < 16; ++i) idx[i] = mi[i]; // broadcast loads

    const float4* src = (const float4*)features + ((size_t)b * F_DIM + f0) * 64 + lane;

    float4 a = make_float4(0.f, 0.f, 0.f, 0.f);
    int cur = idx[0];
    int n = 0;
    #pragma unroll
    for (int h = 0; h < 2; ++h) {
        float4 v[8];
        #pragma unroll
        for (int i = 0; i < 8; ++i) v[i] = src[(h * 8 + i) * 64];  // 8 independent loads
        #pragma unroll
        for (int i = 0; i < 8; ++i) {
            const int id = idx[h * 8 + i];
            if (id != cur) {                     // wave-uniform branch
                flush_run(sums, cnt, b * M_DIM + cur, a, n, lane);
                a = make_float4(0.f, 0.f, 0.f, 0.f);
                n = 0;
                cur = id;
            }
            a.x += v[i].x; a.y += v[i].y; a.z += v[i].z; a.w += v[i].w;
            ++n;
        }
    }
    flush_run(sums, cnt, b * M_DIM + cur, a, n, lane);
}

// ---------------------------------------------------------------------------
// K3 finish: per mora gm: x = concat(emb[vowels[gm]], sums[gm]/cnt[gm]);
// out[gm] = x.Wc + bc. Wc fragments preloaded into REGISTERS (no LDS, no
// bank conflicts). 256 blocks x 4 waves x 8 moras. One coalesced float4
// sums read per mora; butterfly reduce over 64 lanes; lane 0 stores 2xfloat4.
// ---------------------------------------------------------------------------
__global__ __launch_bounds__(256) void finish_kernel(
    const int* __restrict__ vowels,              // [B,M] = [8192]
    const float* __restrict__ emb,               // [V,VE]
    const float* __restrict__ WcT,               // [8,320]
    const float* __restrict__ bc,                // [8]
    const float* __restrict__ sums,              // [8192,256]
    const float* __restrict__ cnt,               // [8192]
    float* __restrict__ out)                     // [8192,8]
{
    const int lane   = threadIdx.x & 63;
    const int wv     = threadIdx.x >> 6;
    const int m_base = blockIdx.x * 32 + wv * 8;

    // Per-lane Wc fragments: mean part k = 64+4*lane+c, emb part k = 4*(lane&15)+c
    float Wm[OUT_DIM][4], We[OUT_DIM][4];
    #pragma unroll
    for (int o = 0; o < OUT_DIM; ++o) {
        const float4 t = *(const float4*)&WcT[o * K_DIM + VE_DIM + lane * 4];
        Wm[o][0] = t.x; Wm[o][1] = t.y; Wm[o][2] = t.z; Wm[o][3] = t.w;
        const float4 u = *(const float4*)&WcT[o * K_DIM + (lane & 15) * 4];
        We[o][0] = u.x; We[o][1] = u.y; We[o][2] = u.z; We[o][3] = u.w;
    }
    float bcr[OUT_DIM];
    #pragma unroll
    for (int o = 0; o < OUT_DIM; ++o) bcr[o] = bc[o];

    for (int mm = 0; mm < 8; ++mm) {
        const int gm = m_base + mm;
        const float4 s = *(const float4*)&sums[(size_t)gm * D_DIM + lane * 4];
        const float c = cnt[gm];
        const float inv = (c > 0.f) ? 1.0f / c : 0.0f;
        const int vw = vowels[gm];               // broadcast

        float p[OUT_DIM];
        #pragma unroll
        for (int o = 0; o < OUT_DIM; ++o)
            p[o] = (s.x * Wm[o][0] + s.y * Wm[o][1] + s.z * Wm[o][2] + s.w * Wm[o][3]) * inv;

        if (lane < 16) {
            const float4 e = *(const float4*)&emb[vw * VE_DIM + lane * 4];
            #pragma unroll
            for (int o = 0; o < OUT_DIM; ++o)
                p[o] += e.x * We[o][0] + e.y * We[o][1] + e.z * We[o][2] + e.w * We[o][3];
        }

        #pragma unroll
        for (int off = 32; off >= 1; off >>= 1) {
            #pragma unroll
            for (int o = 0; o < OUT_DIM; ++o) p[o] += __shfl_xor(p[o], off, 64);
        }
        if (lane == 0) {
            float4* o4 = (float4*)(out + (size_t)gm * OUT_DIM);
            o4[0] = make_float4(p[0] + bcr[0], p[1] + bcr[1], p[2] + bcr[2], p[3] + bcr[3]);
            o4[1] = make_float4(p[4] + bcr[4], p[5] + bcr[5], p[6] + bcr[6], p[7] + bcr[7]);
        }
    }
}

extern "C" void kernel_launch(void* const* d_in, const int* in_sizes, int n_in,
                              void* d_out, int out_size, void* d_ws, size_t ws_size,
                              hipStream_t stream) {
    const int*   vowels     = (const int*)d_in[0];
    const float* features   = (const float*)d_in[1];
    const int*   mora_index = (const int*)d_in[2];
    const float* emb        = (const float*)d_in[3];
    const float* W_mora     = (const float*)d_in[4];
    const float* b_mora     = (const float*)d_in[5];
    // d_in[6] = W_frame, d_in[7] = b_frame: dead code in the reference (fh is deleted)
    const float* W_post     = (const float*)d_in[8];
    const float* b_post     = (const float*)d_in[9];
    float*       out        = (float*)d_out;

    float* sums = (float*)d_ws;                  // [8192,256]
    float* cnt  = sums + SUMS_FLOATS;            // [8192]
    float* WcT  = cnt + NMORA;                   // [8,320]
    float* bc   = WcT + OUT_DIM * K_DIM;         // [8]

    prep_kernel<<<FOLD_BLOCKS + ZBLOCKS, 256, 0, stream>>>(
        W_mora, b_mora, W_post, b_post, WcT, bc, sums /* zero_base */);
    seg_sum_kernel<<<1024, 256, 0, stream>>>(features, mora_index, sums, cnt);
    finish_kernel<<<256, 256, 0, stream>>>(vowels, emb, WcT, bc, sums, cnt, out);
}

// Round 5
// 121.277 us; speedup vs baseline: 1.2992x; 1.2992x over previous
//
#include <hip/hip_runtime.h>

// Shapes (fixed by the reference): B=16, F=4096, M=512, D=256, VE=64, H=512, V=50, OUT=8
#define B_DIM  16
#define F_DIM  4096
#define M_DIM  512
#define D_DIM  256
#define VE_DIM 64
#define H_DIM  512
#define K_DIM  320   // D + VE
#define OUT_DIM 8

#define NMORA       (B_DIM * M_DIM)          // 8192
#define YSTRIDE     16                       // y row: 8 outputs + cnt, padded to 64 B
#define YFLOATS     (NMORA * YSTRIDE)        // 131072 floats = 512 KB
#define FOLD_BLOCKS 642
#define ZBLOCKS     32                       // 32*256*4 float4 = 131072 floats exactly

// ---------------------------------------------------------------------------
// K1 prep: blocks [0,642): fold WcT[o][k] = sum_j W_mora[k,j]*W_post[j,o]
//          and bc[o] = b_mora.W_post[:,o] + b_post[o]   (wave per (k,o))
//          blocks [642,674): zero y[8192][16]
// ---------------------------------------------------------------------------
__global__ __launch_bounds__(256) void prep_kernel(
    const float* __restrict__ W_mora,            // [320,512]
    const float* __restrict__ b_mora,            // [512]
    const float* __restrict__ W_post,            // [512,8]
    const float* __restrict__ b_post,            // [8]
    float* __restrict__ WcT,                     // [8,320] out
    float* __restrict__ bc,                      // [8] out
    float* __restrict__ y)                       // [8192,16] zeroed
{
    const int blk = blockIdx.x;
    const int tid = threadIdx.x;
    if (blk < FOLD_BLOCKS) {
        const int w    = blk * 4 + (tid >> 6);   // global wave id
        const int lane = tid & 63;
        float sum = 0.f;
        if (w < 2560) {
            const int k = w >> 3, o = w & 7;
            const float* arow = W_mora + k * H_DIM;
            #pragma unroll
            for (int it = 0; it < H_DIM / 64; ++it) {
                const int j = lane + it * 64;
                sum += arow[j] * W_post[j * OUT_DIM + o];
            }
            #pragma unroll
            for (int off = 32; off >= 1; off >>= 1) sum += __shfl_down(sum, off, 64);
            if (lane == 0) WcT[o * K_DIM + k] = sum;
        } else if (w < 2568) {                    // bias fold
            const int o = w - 2560;
            #pragma unroll
            for (int it = 0; it < H_DIM / 64; ++it) {
                const int j = lane + it * 64;
                sum += b_mora[j] * W_post[j * OUT_DIM + o];
            }
            #pragma unroll
            for (int off = 32; off >= 1; off >>= 1) sum += __shfl_down(sum, off, 64);
            if (lane == 0) bc[o] = sum + b_post[o];
        }
    } else {
        const int zb = blk - FOLD_BLOCKS;         // 0..31
        float4* z = (float4*)y;
        #pragma unroll
        for (int j = 0; j < 4; ++j)
            z[zb * 1024 + j * 256 + tid] = make_float4(0.f, 0.f, 0.f, 0.f);
    }
}

// ---------------------------------------------------------------------------
// K2 seg_project: grid 1024x256 (single generation, no LDS, no barriers).
// Wave = 16 contiguous frames. Accumulate float4 over each mora-run in
// registers; at each (wave-uniform) boundary, project the run sum through the
// per-lane Wc fragment (D-part), butterfly-reduce the 8 outputs across the
// wave, and flush with ONE atomic instruction (lanes 0-7: outputs, lane 8:
// frame count) into the mora's 64B-aligned y row. ~3 atomics/wave total.
// ---------------------------------------------------------------------------
__device__ __forceinline__ void flush_run(float* __restrict__ y, int gm,
                                          const float4& a, int n, int lane,
                                          const float (&Wf)[OUT_DIM][4])
{
    float p[OUT_DIM];
    #pragma unroll
    for (int o = 0; o < OUT_DIM; ++o)
        p[o] = a.x * Wf[o][0] + a.y * Wf[o][1] + a.z * Wf[o][2] + a.w * Wf[o][3];
    #pragma unroll
    for (int off = 32; off >= 1; off >>= 1) {
        #pragma unroll
        for (int o = 0; o < OUT_DIM; ++o) p[o] += __shfl_xor(p[o], off, 64);
    }
    float val = p[0];                             // all lanes hold the totals
    #pragma unroll
    for (int o = 1; o < OUT_DIM; ++o) val = (lane == o) ? p[o] : val;
    val = (lane == 8) ? (float)n : val;
    if (lane < 9) atomicAdd(&y[(size_t)gm * YSTRIDE + lane], val);
}

__global__ __launch_bounds__(256) void seg_project_kernel(
    const float* __restrict__ features,          // [B,F,D]
    const int* __restrict__ mora_index,          // [B,F] sorted per batch
    const float* __restrict__ WcT,               // [8,320]
    float* __restrict__ y)                       // [8192,16] (+= via atomics)
{
    const int gw   = blockIdx.x * 4 + (threadIdx.x >> 6);  // 0..4095
    const int lane = threadIdx.x & 63;
    const int b    = gw >> 8;                    // 256 waves per batch
    const int f0   = (gw & 255) * 16;

    // Per-lane Wc fragment for the mean part: Wf[o][c] = Wc[64 + 4*lane + c][o]
    float Wf[OUT_DIM][4];
    #pragma unroll
    for (int o = 0; o < OUT_DIM; ++o) {
        const float4 t = *(const float4*)&WcT[o * K_DIM + VE_DIM + 4 * lane];
        Wf[o][0] = t.x; Wf[o][1] = t.y; Wf[o][2] = t.z; Wf[o][3] = t.w;
    }

    const int* mi = mora_index + b * F_DIM + f0;
    int idx[16];
    #pragma unroll
    for (int i = 0; i < 16; ++i) idx[i] = mi[i]; // wave-uniform -> scalar loads

    const float4* src = (const float4*)features + ((size_t)b * F_DIM + f0) * 64 + lane;

    float4 a = make_float4(0.f, 0.f, 0.f, 0.f);
    int cur = idx[0];
    int n = 0;
    #pragma unroll
    for (int h = 0; h < 2; ++h) {
        float4 v[8];
        #pragma unroll
        for (int i = 0; i < 8; ++i) v[i] = src[(h * 8 + i) * 64];  // 8 loads in flight
        #pragma unroll
        for (int i = 0; i < 8; ++i) {
            const int id = idx[h * 8 + i];
            if (id != cur) {                     // wave-uniform branch
                flush_run(y, b * M_DIM + cur, a, n, lane, Wf);
                a = make_float4(0.f, 0.f, 0.f, 0.f);
                n = 0;
                cur = id;
            }
            a.x += v[i].x; a.y += v[i].y; a.z += v[i].z; a.w += v[i].w;
            ++n;
        }
    }
    flush_run(y, b * M_DIM + cur, a, n, lane, Wf);
}

// ---------------------------------------------------------------------------
// K3 finish: thread per (mora, output): out[gm][o] =
//   y[gm][o]/cnt + sum_c emb[vowel[gm]][c] * Wc[c][o] + bc[o]
// emb/WcT reads are L1-resident (50x64 and 8x320 tables).
// ---------------------------------------------------------------------------
__global__ __launch_bounds__(256) void finish_kernel(
    const int* __restrict__ vowels,              // [8192]
    const float* __restrict__ emb,               // [V,VE]
    const float* __restrict__ WcT,               // [8,320]
    const float* __restrict__ bc,                // [8]
    const float* __restrict__ y,                 // [8192,16]
    float* __restrict__ out)                     // [8192,8]
{
    const int t  = blockIdx.x * 256 + threadIdx.x;  // 0..65535
    const int gm = t >> 3;
    const int o  = t & 7;
    const float cnt = y[gm * YSTRIDE + 8];
    const float inv = (cnt > 0.f) ? 1.0f / cnt : 0.0f;
    const int vw = vowels[gm];
    float r = y[gm * YSTRIDE + o] * inv + bc[o];
    const float* e = emb + vw * VE_DIM;
    const float* w = WcT + o * K_DIM;            // emb part: k = 0..63
    #pragma unroll
    for (int c = 0; c < VE_DIM; ++c) r += e[c] * w[c];
    out[t] = r;
}

extern "C" void kernel_launch(void* const* d_in, const int* in_sizes, int n_in,
                              void* d_out, int out_size, void* d_ws, size_t ws_size,
                              hipStream_t stream) {
    const int*   vowels     = (const int*)d_in[0];
    const float* features   = (const float*)d_in[1];
    const int*   mora_index = (const int*)d_in[2];
    const float* emb        = (const float*)d_in[3];
    const float* W_mora     = (const float*)d_in[4];
    const float* b_mora     = (const float*)d_in[5];
    // d_in[6] = W_frame, d_in[7] = b_frame: dead code in the reference (fh is deleted)
    const float* W_post     = (const float*)d_in[8];
    const float* b_post     = (const float*)d_in[9];
    float*       out        = (float*)d_out;

    float* y   = (float*)d_ws;                   // [8192,16] (512 KB)
    float* WcT = y + YFLOATS;                    // [8,320]
    float* bc  = WcT + OUT_DIM * K_DIM;          // [8]

    prep_kernel<<<FOLD_BLOCKS + ZBLOCKS, 256, 0, stream>>>(
        W_mora, b_mora, W_post, b_post, WcT, bc, y);
    seg_project_kernel<<<1024, 256, 0, stream>>>(features, mora_index, WcT, y);
    finish_kernel<<<NMORA * OUT_DIM / 256, 256, 0, stream>>>(
        vowels, emb, WcT, bc, y, out);
}

// Round 6
// 118.593 us; speedup vs baseline: 1.3286x; 1.0226x over previous
//
#include <hip/hip_runtime.h>

// Shapes (fixed by the reference): B=16, F=4096, M=512, D=256, VE=64, H=512, V=50, OUT=8
#define B_DIM  16
#define F_DIM  4096
#define M_DIM  512
#define D_DIM  256
#define VE_DIM 64
#define H_DIM  512
#define K_DIM  320   // D + VE
#define OUT_DIM 8

#define NMORA       (B_DIM * M_DIM)          // 8192
#define YSTRIDE     16                       // y row: 8 outputs + cnt, padded to 64 B
#define YFLOATS     (NMORA * YSTRIDE)        // 131072 floats = 512 KB
#define FOLD_BLOCKS 81                       // 81*4 = 324 waves >= 321 needed
#define ZBLOCKS     32                       // 32*256*4 float4 = 131072 floats exactly

// Two-stage 64-lane reduction of 8 channels:
//   stage 1: xor {1,2,4} on all 8 -> each 8-lane group holds its group-sums
//   select:  lane picks channel (lane&7)
//   stage 2: xor {8,16,32} on one value -> lane l holds total of channel l&7
__device__ __forceinline__ float reduce8(float (&p)[OUT_DIM], int lane) {
    #pragma unroll
    for (int off = 1; off <= 4; off <<= 1) {
        #pragma unroll
        for (int o = 0; o < OUT_DIM; ++o) p[o] += __shfl_xor(p[o], off, 64);
    }
    const int s = lane & 7;
    float val = p[0];
    #pragma unroll
    for (int o = 1; o < OUT_DIM; ++o) val = (s == o) ? p[o] : val;
    val += __shfl_xor(val, 8, 64);
    val += __shfl_xor(val, 16, 64);
    val += __shfl_xor(val, 32, 64);
    return val;
}

// ---------------------------------------------------------------------------
// K1 prep: blocks [0,81): wave w<320 folds row k=w: WcT[o][k] = W_mora[k,:].W_post[:,o]
//          (reads W_mora exactly once); wave 320 folds bc = b_mora.W_post + b_post.
//          blocks [81,113): zero y[8192][16].
// ---------------------------------------------------------------------------
__global__ __launch_bounds__(256) void prep_kernel(
    const float* __restrict__ W_mora,            // [320,512]
    const float* __restrict__ b_mora,            // [512]
    const float* __restrict__ W_post,            // [512,8]
    const float* __restrict__ b_post,            // [8]
    float* __restrict__ WcT,                     // [8,320] out
    float* __restrict__ bc,                      // [8] out
    float* __restrict__ y)                       // [8192,16] zeroed
{
    const int blk = blockIdx.x;
    const int tid = threadIdx.x;
    if (blk < FOLD_BLOCKS) {
        const int w    = blk * 4 + (tid >> 6);   // 0..323
        const int lane = tid & 63;
        if (w <= 320) {
            const float* arow = (w < 320) ? (W_mora + w * H_DIM) : b_mora;
            float acc[OUT_DIM] = {0.f, 0.f, 0.f, 0.f, 0.f, 0.f, 0.f, 0.f};
            #pragma unroll
            for (int it = 0; it < H_DIM / 64; ++it) {
                const int j = it * 64 + lane;
                const float aval = arow[j];
                const float4 w0 = *(const float4*)&W_post[j * OUT_DIM];
                const float4 w1 = *(const float4*)&W_post[j * OUT_DIM + 4];
                acc[0] += aval * w0.x; acc[1] += aval * w0.y;
                acc[2] += aval * w0.z; acc[3] += aval * w0.w;
                acc[4] += aval * w1.x; acc[5] += aval * w1.y;
                acc[6] += aval * w1.z; acc[7] += aval * w1.w;
            }
            const float val = reduce8(acc, lane);
            if (lane < OUT_DIM) {
                if (w < 320) WcT[lane * K_DIM + w] = val;
                else         bc[lane] = val + b_post[lane];
            }
        }
    } else {
        const int zb = blk - FOLD_BLOCKS;         // 0..31
        float4* z = (float4*)y;
        #pragma unroll
        for (int j = 0; j < 4; ++j)
            z[zb * 1024 + j * 256 + tid] = make_float4(0.f, 0.f, 0.f, 0.f);
    }
}

// ---------------------------------------------------------------------------
// K2 seg_project: grid 512x256 = 2 blocks/CU, one generation, no LDS/barriers.
// Wave = 32 contiguous frames of one batch. Accumulate float4 per mora-run in
// registers; at each (wave-uniform) run boundary project through the per-lane
// Wc fragment, two-stage reduce, and flush with ONE 9-lane atomic instruction
// (outputs + frame count) into the mora's 64B y row. ~5 flushes per wave.
// ---------------------------------------------------------------------------
__device__ __forceinline__ void flush_run(float* __restrict__ y, int gm,
                                          const float4& a, int n, int lane,
                                          const float (&Wf)[OUT_DIM][4])
{
    float p[OUT_DIM];
    #pragma unroll
    for (int o = 0; o < OUT_DIM; ++o)
        p[o] = a.x * Wf[o][0] + a.y * Wf[o][1] + a.z * Wf[o][2] + a.w * Wf[o][3];
    float val = reduce8(p, lane);
    val = (lane == 8) ? (float)n : val;
    if (lane < 9) atomicAdd(&y[(size_t)gm * YSTRIDE + lane], val);
}

__global__ __launch_bounds__(256) void seg_project_kernel(
    const float* __restrict__ features,          // [B,F,D]
    const int* __restrict__ mora_index,          // [B,F] sorted per batch
    const float* __restrict__ WcT,               // [8,320]
    float* __restrict__ y)                       // [8192,16] (+= via atomics)
{
    const int gw   = blockIdx.x * 4 + (threadIdx.x >> 6);  // 0..2047
    const int lane = threadIdx.x & 63;
    const int b    = gw >> 7;                    // 128 waves per batch
    const int f0   = (gw & 127) * 32;

    // Per-lane Wc fragment for the mean part: Wf[o][c] = Wc[64 + 4*lane + c][o]
    float Wf[OUT_DIM][4];
    #pragma unroll
    for (int o = 0; o < OUT_DIM; ++o) {
        const float4 t = *(const float4*)&WcT[o * K_DIM + VE_DIM + 4 * lane];
        Wf[o][0] = t.x; Wf[o][1] = t.y; Wf[o][2] = t.z; Wf[o][3] = t.w;
    }

    // 32 mora indices via 8 int4 loads (same address across lanes -> broadcast)
    int idx[32];
    const int4* mi4 = (const int4*)(mora_index + b * F_DIM + f0);
    #pragma unroll
    for (int i = 0; i < 8; ++i) {
        const int4 t = mi4[i];
        idx[4 * i + 0] = t.x; idx[4 * i + 1] = t.y;
        idx[4 * i + 2] = t.z; idx[4 * i + 3] = t.w;
    }

    const float4* src = (const float4*)features + ((size_t)b * F_DIM + f0) * 64 + lane;

    float4 a = make_float4(0.f, 0.f, 0.f, 0.f);
    int cur = idx[0];
    int n = 0;
    #pragma unroll
    for (int h = 0; h < 4; ++h) {
        float4 v[8];
        #pragma unroll
        for (int i = 0; i < 8; ++i) v[i] = src[(h * 8 + i) * 64];  // 8 loads in flight
        #pragma unroll
        for (int i = 0; i < 8; ++i) {
            const int id = idx[h * 8 + i];
            if (id != cur) {                     // wave-uniform branch
                flush_run(y, b * M_DIM + cur, a, n, lane, Wf);
                a = make_float4(0.f, 0.f, 0.f, 0.f);
                n = 0;
                cur = id;
            }
            a.x += v[i].x; a.y += v[i].y; a.z += v[i].z; a.w += v[i].w;
            ++n;
        }
    }
    flush_run(y, b * M_DIM + cur, a, n, lane, Wf);
}

// ---------------------------------------------------------------------------
// K3 finish: thread per (mora, output): out[gm][o] =
//   y[gm][o]/cnt + emb[vowel[gm]] . Wc[0:64][o] + bc[o]
// emb/WcT are L1-resident; float4 dot over the 64-dim emb part.
// ---------------------------------------------------------------------------
__global__ __launch_bounds__(256) void finish_kernel(
    const int* __restrict__ vowels,              // [8192]
    const float* __restrict__ emb,               // [V,VE]
    const float* __restrict__ WcT,               // [8,320]
    const float* __restrict__ bc,                // [8]
    const float* __restrict__ y,                 // [8192,16]
    float* __restrict__ out)                     // [8192,8]
{
    const int t  = blockIdx.x * 256 + threadIdx.x;  // 0..65535
    const int gm = t >> 3;
    const int o  = t & 7;
    const float cnt = y[gm * YSTRIDE + 8];
    const float inv = (cnt > 0.f) ? 1.0f / cnt : 0.0f;
    const int vw = vowels[gm];
    float r = y[gm * YSTRIDE + o] * inv + bc[o];
    const float4* e4 = (const float4*)(emb + vw * VE_DIM);
    const float4* w4 = (const float4*)(WcT + o * K_DIM);  // emb part: k = 0..63
    #pragma unroll
    for (int c = 0; c < VE_DIM / 4; ++c) {
        const float4 ev = e4[c];
        const float4 wv = w4[c];
        r += ev.x * wv.x + ev.y * wv.y + ev.z * wv.z + ev.w * wv.w;
    }
    out[t] = r;
}

extern "C" void kernel_launch(void* const* d_in, const int* in_sizes, int n_in,
                              void* d_out, int out_size, void* d_ws, size_t ws_size,
                              hipStream_t stream) {
    const int*   vowels     = (const int*)d_in[0];
    const float* features   = (const float*)d_in[1];
    const int*   mora_index = (const int*)d_in[2];
    const float* emb        = (const float*)d_in[3];
    const float* W_mora     = (const float*)d_in[4];
    const float* b_mora     = (const float*)d_in[5];
    // d_in[6] = W_frame, d_in[7] = b_frame: dead code in the reference (fh is deleted)
    const float* W_post     = (const float*)d_in[8];
    const float* b_post     = (const float*)d_in[9];
    float*       out        = (float*)d_out;

    float* y   = (float*)d_ws;                   // [8192,16] (512 KB)
    float* WcT = y + YFLOATS;                    // [8,320]
    float* bc  = WcT + OUT_DIM * K_DIM;          // [8]

    prep_kernel<<<FOLD_BLOCKS + ZBLOCKS, 256, 0, stream>>>(
        W_mora, b_mora, W_post, b_post, WcT, bc, y);
    seg_project_kernel<<<512, 256, 0, stream>>>(features, mora_index, WcT, y);
    finish_kernel<<<NMORA * OUT_DIM / 256, 256, 0, stream>>>(
        vowels, emb, WcT, bc, y, out);
}